// Round 4
// baseline (130.527 us; speedup 1.0000x reference)
//
#include <hip/hip_runtime.h>

// FANS: B=131072 rows x 16 states, MLP 12->64->64->1 with tanh, fp32 in/out.
// R21: three levers on top of R20's LDS-weight structure (66us, occ 48%,
// VALUBusy 62%, WRITE 38MB):
// (1) Fused tanh->kc pipeline: each kc consumes a disjoint pw group
//     (kc0<-c1a[0..7], kc1<-c1a[8..15], kc2<-c1b[0..7], kc3<-c1b[8..15]),
//     so build 4 tanh words -> 2 permlane swaps -> 2 MFMAs per kc instead of
//     all 16 pw upfront: first layer-2 MFMA issues 4x earlier, peak live
//     regs drop ~12-16.
// (2) __launch_bounds__(256,6): with (1), peak unified ~70-80 <= 85 ->
//     6 waves/SIMD feasible (R19 lesson: FETCH_SIZE is the spill tripwire).
// (3) XCD write-combine swizzle: out[row*16+s] writes 4B/64B-line; the 16
//     states of a row-range are 16 different blocks. Remap 1D grid so those
//     16 blocks get ids = same mod 8 -> same XCD (round-robin) -> L2 merges
//     them into full lines. Predict WRITE 38->~12MB; also L2 read reuse.
// Kept: permlane32_swap H-exchange, 32x32x16 MFMA both layers, pk-f16 tanh,
// weights staged to LDS in frag layout, opaque-zero anti-LICM, CHUNK=4,
// zpl planes (wave-local, no barrier), split fdot2 accums.
// Tripwires: FETCH>>10MB -> spill, revert bound to 5; WRITE flat -> XCD
// round-robin assumption wrong, drop swizzle; absmax must stay 0.00098.

#define N_STATES 16
#define CHUNK    4

typedef _Float16 f16x8  __attribute__((ext_vector_type(8)));
typedef float    f32x16 __attribute__((ext_vector_type(16)));
typedef __fp16   h2     __attribute__((ext_vector_type(2)));
typedef unsigned int u32x2 __attribute__((ext_vector_type(2)));

__device__ __forceinline__ h2 pack2(float a, float b) {
    return __builtin_amdgcn_cvt_pkrtz(a, b);
}
__device__ __forceinline__ unsigned int h2_bits(h2 v) {
    union { h2 h; unsigned int u; } x; x.h = v; return x.u;
}
__device__ __forceinline__ h2 bits_h2(unsigned int v) {
    union { unsigned int u; h2 h; } x; x.u = v; return x.h;
}
__device__ __forceinline__ f16x8 u4_to_h8(uint4 v) {
    union { uint4 u; f16x8 h; } x; x.u = v; return x.h;
}
__device__ __forceinline__ uint4 pk8(float4 a, float4 b) {
    return make_uint4(h2_bits(pack2(a.x, a.y)), h2_bits(pack2(a.z, a.w)),
                      h2_bits(pack2(b.x, b.y)), h2_bits(pack2(b.z, b.w)));
}

// Packed-f16 tanh: clamp(+-1.25) then odd Chebyshev poly; v_pk_* full-rate.
__device__ __forceinline__ h2 tanh_pk(h2 x) {
    const h2 hi = {(__fp16)1.25f, (__fp16)1.25f};
    const h2 lo = {(__fp16)-1.25f, (__fp16)-1.25f};
    x = __builtin_elementwise_min(__builtin_elementwise_max(x, lo), hi);
    h2 s = x * x;
    const h2 c4 = {(__fp16)0.00598591f, (__fp16)0.00598591f};
    const h2 c3 = {(__fp16)-0.03807894f, (__fp16)-0.03807894f};
    const h2 c2 = {(__fp16)0.12576901f, (__fp16)0.12576901f};
    const h2 c1 = {(__fp16)-0.33203310f, (__fp16)-0.33203310f};
    const h2 c0 = {(__fp16)0.99998110f, (__fp16)0.99998110f};
    h2 p = s * c4 + c3;
    p = s * p + c2;
    p = s * p + c1;
    p = s * p + c0;
    return x * p;
}

__global__ __launch_bounds__(256, 6) void fans_mfma_kernel(
    const float* __restrict__ x_f, const float* __restrict__ x_b,
    const float* __restrict__ u,   const float* __restrict__ W0,
    const float* __restrict__ W1,  const float* __restrict__ W2,
    float* __restrict__ out)
{
    __shared__ __align__(16) uint4 zplA[256];              // 4 KB: z dwords 0..3
    __shared__ __align__(16) uint2 zplB[256];              // 2 KB: u pair
    __shared__ __align__(16) uint4 sA1[8][64];             // 8 KB: W1 frags [Mh*4+kc][h*32+n]
    __shared__ __align__(16) uint4 sA0[2][64];             // 2 KB: W0 frags [Mh][h*32+n]
    __shared__ __align__(16) unsigned int w2l[32];         // 128 B: W2 pair-packed

    // ---- XCD write-combine swizzle: 16 blocks of one row-group (all 16
    // states) -> same XCD. bid = xcd + 8*((g>>3)*16 + j), g=row-group, j=s.
    const int bid = blockIdx.x;
    const int xcd = bid & 7;
    const int t   = bid >> 3;
    const int s   = t & 15;                       // state
    const int g   = (t >> 4) * 8 + xcd;           // row-group 0..127
    const int tid = threadIdx.x;
    const int b0  = g * (256 * CHUNK);

    const int lid = tid & 63;
    const int w   = tid >> 6;     // wave id; wave w owns local rows [64w,64w+64)
    const int n   = lid & 31;     // batch row within 32-tile / feat row for A
    const int h   = lid >> 5;     // K-half (k = 8h+j)

    // ---- stage weights to LDS in frag layout (once per block) ----
    // sA1[Mh*4+kc][h*32+n] = W1[s][32Mh+n][16kc+8h+0..7] as 8 x f16
    {
        const int r  = tid >> 2;          // 0..63 feature row
        const int kc = tid & 3;           // 0..3 K-chunk
        const float* p = W1 + s * 4096 + r * 64 + kc * 16;
        const float4 v0 = ((const float4*)p)[0];
        const float4 v1 = ((const float4*)p)[1];
        const float4 v2 = ((const float4*)p)[2];
        const float4 v3 = ((const float4*)p)[3];
        sA1[(r >> 5) * 4 + kc][(r & 31)]      = pk8(v0, v1);  // h=0: cols +0..7
        sA1[(r >> 5) * 4 + kc][32 + (r & 31)] = pk8(v2, v3);  // h=1: cols +8..15
    }
    // sA0[Mh][h*32+n] = W0[s][32Mh+n][8h+0..7] (h=1: cols 8..11 + zero pad)
    if (tid < 128) {
        const int r  = tid >> 1;          // 0..63 feature row
        const int hh = tid & 1;
        const float* base = W0 + s * 768 + r * 12;
        uint4 v;
        if (hh == 0) {
            const float4 v0 = *(const float4*)(base + 0);
            const float4 v1 = *(const float4*)(base + 4);
            v = pk8(v0, v1);
        } else {
            const float4 v0 = *(const float4*)(base + 8);   // k=8..11
            v = make_uint4(h2_bits(pack2(v0.x, v0.y)), h2_bits(pack2(v0.z, v0.w)), 0u, 0u);
        }
        sA0[r >> 5][hh * 32 + (r & 31)] = v;
    }
    // w2l[i] = pack2(W2[s][2i], W2[s][2i+1]); layer-3 reads broadcast per h.
    if (tid < 32) {
        const float* w2s = W2 + s * 64;
        w2l[tid] = h2_bits(pack2(w2s[2 * tid], w2s[2 * tid + 1]));
    }
    __syncthreads();

    const int wrap = (s > 8) ? (s - 8) : 0;   // IDX[s] = {0..wrap-1}++{s..15}

    #pragma unroll 1
    for (int ch = 0; ch < CHUNK; ++ch) {
        const int rbase = b0 + ch * 256;

        // ---- phase 1: gather z for own row, pack, write planes ----
        {
            const int row = rbase + tid;
            float zs[8];
            #pragma unroll
            for (int j = 0; j < 8; ++j) {
                const int idx = (j < wrap) ? j : (s + j - wrap);  // uniform
                zs[j] = (idx < 8) ? x_f[row * 8 + idx] : x_b[row * 8 + (idx - 8)];
            }
            const float4 uv = *(const float4*)(u + row * 4);
            zplA[tid] = make_uint4(h2_bits(pack2(zs[0], zs[1])), h2_bits(pack2(zs[2], zs[3])),
                                   h2_bits(pack2(zs[4], zs[5])), h2_bits(pack2(zs[6], zs[7])));
            zplB[tid] = make_uint2(h2_bits(pack2(uv.x, uv.y)), h2_bits(pack2(uv.z, uv.w)));
        }
        // No barrier: wave w reads only rows [64w,64w+64) it wrote itself;
        // weight LDS is read-only after the initial sync.

        // ---- phase 2: two 32-row tiles ----
        #pragma unroll
        for (int m = 0; m < 2; ++m) {
            const int rowb = 64 * w + 32 * m;

            // Opaque zero: defeats LICM/CSE so weight ds_reads stay per-tile
            // (normal HIP loads -> compiler manages lgkmcnt; just un-hoistable).
            unsigned int zero = 0;
            asm("" : "+v"(zero));
            const int lz = lid + (int)zero;

            // z B-frag: B[k=8h+j][n]: h=0 -> z dwords 0..3; h=1 -> u pair + 0
            f16x8 zf;
            if (h == 0) {
                zf = u4_to_h8(zplA[rowb + n]);
            } else {
                const uint2 b = zplB[rowb + n];
                zf = u4_to_h8(make_uint4(b.x, b.y, 0u, 0u));
            }

            // layer 1: 2 MFMAs (M-halves), C1[Mh][r] = feat 32Mh+(r&3)+8(r>>2)+4h, col n
            const f32x16 z16 = {0.f,0.f,0.f,0.f,0.f,0.f,0.f,0.f,
                                0.f,0.f,0.f,0.f,0.f,0.f,0.f,0.f};
            const f16x8 a0a = u4_to_h8(sA0[0][lz]);
            const f16x8 a0b = u4_to_h8(sA0[1][lz]);
            f32x16 c1a = __builtin_amdgcn_mfma_f32_32x32x16_f16(a0a, zf, z16, 0, 0, 0);
            f32x16 c1b = __builtin_amdgcn_mfma_f32_32x32x16_f16(a0b, zf, z16, 0, 0, 0);

            // layer 2, fused with layer-1 tanh: each kc consumes a disjoint
            // 8-value slice of c1 (kc0: c1a[0..7], kc1: c1a[8..15],
            // kc2: c1b[0..7], kc3: c1b[8..15]): 4 tanh_pk -> 2 half-swaps
            // (swap(A,B) -> ({A.lo,B.lo},{A.hi,B.hi})) -> 2 MFMAs.
            f32x16 c2a = z16, c2b = z16;
            #pragma unroll
            for (int kc = 0; kc < 4; ++kc) {
                const f32x16 c1s = (kc < 2) ? c1a : c1b;   // compile-time after unroll
                const int r = (kc & 1) * 8;
                const unsigned int t0 = h2_bits(tanh_pk(pack2(c1s[r],     c1s[r + 1])));
                const unsigned int t1 = h2_bits(tanh_pk(pack2(c1s[r + 2], c1s[r + 3])));
                const unsigned int t2 = h2_bits(tanh_pk(pack2(c1s[r + 4], c1s[r + 5])));
                const unsigned int t3 = h2_bits(tanh_pk(pack2(c1s[r + 6], c1s[r + 7])));
                u32x2 r0 = __builtin_amdgcn_permlane32_swap(t0, t2, false, false);
                u32x2 r1 = __builtin_amdgcn_permlane32_swap(t1, t3, false, false);
                const f16x8 hb  = u4_to_h8(make_uint4(r0.x, r1.x, r0.y, r1.y));
                const f16x8 w1a = u4_to_h8(sA1[kc][lz]);
                const f16x8 w1b = u4_to_h8(sA1[4 + kc][lz]);
                c2a = __builtin_amdgcn_mfma_f32_32x32x16_f16(w1a, hb, c2a, 0, 0, 0);
                c2b = __builtin_amdgcn_mfma_f32_32x32x16_f16(w1b, hb, c2b, 0, 0, 0);
            }

            // layer 3: packed tanh + v_dot2; W2 pairs broadcast-read from LDS.
            // Split accumulators: 2-deep chains instead of 4-deep.
            const unsigned int* w2z = &w2l[zero];
            float p0 = 0.f, p1 = 0.f, q0 = 0.f, q1 = 0.f;
            #pragma unroll
            for (int a = 0; a < 4; ++a) {
                const int r = 4 * a;
                const uint2 wa = *(const uint2*)&w2z[4 * a + 2 * h];        // Mh=0
                const uint2 wb = *(const uint2*)&w2z[16 + 4 * a + 2 * h];   // Mh=1
                if (a & 1) {
                    p1 = __builtin_amdgcn_fdot2(tanh_pk(pack2(c2a[r], c2a[r + 1])), bits_h2(wa.x), p1, false);
                    p1 = __builtin_amdgcn_fdot2(tanh_pk(pack2(c2a[r + 2], c2a[r + 3])), bits_h2(wa.y), p1, false);
                    q1 = __builtin_amdgcn_fdot2(tanh_pk(pack2(c2b[r], c2b[r + 1])), bits_h2(wb.x), q1, false);
                    q1 = __builtin_amdgcn_fdot2(tanh_pk(pack2(c2b[r + 2], c2b[r + 3])), bits_h2(wb.y), q1, false);
                } else {
                    p0 = __builtin_amdgcn_fdot2(tanh_pk(pack2(c2a[r], c2a[r + 1])), bits_h2(wa.x), p0, false);
                    p0 = __builtin_amdgcn_fdot2(tanh_pk(pack2(c2a[r + 2], c2a[r + 3])), bits_h2(wa.y), p0, false);
                    q0 = __builtin_amdgcn_fdot2(tanh_pk(pack2(c2b[r], c2b[r + 1])), bits_h2(wb.x), q0, false);
                    q0 = __builtin_amdgcn_fdot2(tanh_pk(pack2(c2b[r + 2], c2b[r + 3])), bits_h2(wb.y), q0, false);
                }
            }
            float acc = (p0 + p1) + (q0 + q1);
            acc += __shfl_xor(acc, 32);       // combine h=0/h=1 halves

            if (lid < 32)
                out[(rbase + rowb + n) * N_STATES + s] = acc;
        }
    }
}

extern "C" void kernel_launch(void* const* d_in, const int* in_sizes, int n_in,
                              void* d_out, int out_size, void* d_ws, size_t ws_size,
                              hipStream_t stream) {
    const float* x_f = (const float*)d_in[0];
    const float* x_b = (const float*)d_in[1];
    const float* u   = (const float*)d_in[2];
    const float* W0  = (const float*)d_in[3];
    const float* W1  = (const float*)d_in[4];
    const float* W2  = (const float*)d_in[5];
    float* out = (float*)d_out;

    const int nb = in_sizes[0] / 8;                 // 131072 rows
    const int nblk = (nb / (256 * CHUNK)) * N_STATES;   // 128*16 = 2048, %8==0
    fans_mfma_kernel<<<dim3(nblk), 256, 0, stream>>>(x_f, x_b, u, W0, W1, W2, out);
}

// Round 6
// 122.327 us; speedup vs baseline: 1.0670x; 1.0670x over previous
//
#include <hip/hip_runtime.h>

// FANS: B=131072 rows x 16 states, MLP 12->64->64->1 with tanh, fp32 in/out.
// R22 (resubmit; previous round was an infra failure, no data): R20 base +
// sequential c1-half lifetimes. R21 post-mortem: fusion kept c1a+c1b+c2a+c2b
// (64 accums) live across the kc loop and +4 arch VGPRs crossed a waves/SIMD
// boundary (occ 48->43, dur 66->75). Also proven there: FETCH ~6.5MB vs 10MB
// input (L3-resident) and WRITE not time-limiting -> this kernel is pure
// VALU-throughput x occupancy; VALU busy-time ~42us is the work, currently
// packed at only 62%.
// Change: per tile, c1 halves are computed AND consumed sequentially:
//   c1 = MFMA(a0a) -> 8 tanh words -> kc0,kc1 -> [sched_barrier]
//   c1 = MFMA(a0b) -> 8 tanh words -> kc2,kc3
// sched_barrier(0) pins stop the scheduler re-hoisting the 2nd MFMA, so both
// halves share one 16-reg accum + only 8 pw words live -> peak accum ~48,
// unified ~84-88 -> 5-6 waves/SIMD (was 4). Swizzle dropped (writes
// non-limiting; clean attribution). kc->pw slicing identical to R21 (passed).
// Kept: permlane32_swap H-exchange, 32x32x16 MFMA, pk-f16 tanh, weights in
// LDS frag layout, opaque-zero anti-LICM, CHUNK=4, split fdot2 accums.
// Tripwires: FETCH>>10MB -> spill; occupancy flat ~45% w/o spill -> reg-cap
// theory falsified, pivot to VALU-op reduction.

#define N_STATES 16
#define CHUNK    4

typedef _Float16 f16x8  __attribute__((ext_vector_type(8)));
typedef float    f32x16 __attribute__((ext_vector_type(16)));
typedef __fp16   h2     __attribute__((ext_vector_type(2)));
typedef unsigned int u32x2 __attribute__((ext_vector_type(2)));

__device__ __forceinline__ h2 pack2(float a, float b) {
    return __builtin_amdgcn_cvt_pkrtz(a, b);
}
__device__ __forceinline__ unsigned int h2_bits(h2 v) {
    union { h2 h; unsigned int u; } x; x.h = v; return x.u;
}
__device__ __forceinline__ h2 bits_h2(unsigned int v) {
    union { unsigned int u; h2 h; } x; x.u = v; return x.h;
}
__device__ __forceinline__ f16x8 u4_to_h8(uint4 v) {
    union { uint4 u; f16x8 h; } x; x.u = v; return x.h;
}
__device__ __forceinline__ uint4 pk8(float4 a, float4 b) {
    return make_uint4(h2_bits(pack2(a.x, a.y)), h2_bits(pack2(a.z, a.w)),
                      h2_bits(pack2(b.x, b.y)), h2_bits(pack2(b.z, b.w)));
}

// Packed-f16 tanh: clamp(+-1.25) then odd Chebyshev poly; v_pk_* full-rate.
__device__ __forceinline__ h2 tanh_pk(h2 x) {
    const h2 hi = {(__fp16)1.25f, (__fp16)1.25f};
    const h2 lo = {(__fp16)-1.25f, (__fp16)-1.25f};
    x = __builtin_elementwise_min(__builtin_elementwise_max(x, lo), hi);
    h2 s = x * x;
    const h2 c4 = {(__fp16)0.00598591f, (__fp16)0.00598591f};
    const h2 c3 = {(__fp16)-0.03807894f, (__fp16)-0.03807894f};
    const h2 c2 = {(__fp16)0.12576901f, (__fp16)0.12576901f};
    const h2 c1 = {(__fp16)-0.33203310f, (__fp16)-0.33203310f};
    const h2 c0 = {(__fp16)0.99998110f, (__fp16)0.99998110f};
    h2 p = s * c4 + c3;
    p = s * p + c2;
    p = s * p + c1;
    p = s * p + c0;
    return x * p;
}

__global__ __launch_bounds__(256, 6) void fans_mfma_kernel(
    const float* __restrict__ x_f, const float* __restrict__ x_b,
    const float* __restrict__ u,   const float* __restrict__ W0,
    const float* __restrict__ W1,  const float* __restrict__ W2,
    float* __restrict__ out)
{
    __shared__ __align__(16) uint4 zplA[256];              // 4 KB: z dwords 0..3
    __shared__ __align__(16) uint2 zplB[256];              // 2 KB: u pair
    __shared__ __align__(16) uint4 sA1[8][64];             // 8 KB: W1 frags [Mh*4+kc][h*32+n]
    __shared__ __align__(16) uint4 sA0[2][64];             // 2 KB: W0 frags [Mh][h*32+n]
    __shared__ __align__(16) unsigned int w2l[32];         // 128 B: W2 pair-packed

    const int s   = blockIdx.y;
    const int tid = threadIdx.x;
    const int b0  = blockIdx.x * (256 * CHUNK);

    const int lid = tid & 63;
    const int w   = tid >> 6;     // wave id; wave w owns local rows [64w,64w+64)
    const int n   = lid & 31;     // batch row within 32-tile / feat row for A
    const int h   = lid >> 5;     // K-half (k = 8h+j)

    // ---- stage weights to LDS in frag layout (once per block) ----
    // sA1[Mh*4+kc][h*32+n] = W1[s][32Mh+n][16kc+8h+0..7] as 8 x f16
    {
        const int r  = tid >> 2;          // 0..63 feature row
        const int kc = tid & 3;           // 0..3 K-chunk
        const float* p = W1 + s * 4096 + r * 64 + kc * 16;
        const float4 v0 = ((const float4*)p)[0];
        const float4 v1 = ((const float4*)p)[1];
        const float4 v2 = ((const float4*)p)[2];
        const float4 v3 = ((const float4*)p)[3];
        sA1[(r >> 5) * 4 + kc][(r & 31)]      = pk8(v0, v1);  // h=0: cols +0..7
        sA1[(r >> 5) * 4 + kc][32 + (r & 31)] = pk8(v2, v3);  // h=1: cols +8..15
    }
    // sA0[Mh][h*32+n] = W0[s][32Mh+n][8h+0..7] (h=1: cols 8..11 + zero pad)
    if (tid < 128) {
        const int r  = tid >> 1;          // 0..63 feature row
        const int hh = tid & 1;
        const float* base = W0 + s * 768 + r * 12;
        uint4 v;
        if (hh == 0) {
            const float4 v0 = *(const float4*)(base + 0);
            const float4 v1 = *(const float4*)(base + 4);
            v = pk8(v0, v1);
        } else {
            const float4 v0 = *(const float4*)(base + 8);   // k=8..11
            v = make_uint4(h2_bits(pack2(v0.x, v0.y)), h2_bits(pack2(v0.z, v0.w)), 0u, 0u);
        }
        sA0[r >> 5][hh * 32 + (r & 31)] = v;
    }
    // w2l[i] = pack2(W2[s][2i], W2[s][2i+1]); layer-3 reads broadcast per h.
    if (tid < 32) {
        const float* w2s = W2 + s * 64;
        w2l[tid] = h2_bits(pack2(w2s[2 * tid], w2s[2 * tid + 1]));
    }
    __syncthreads();

    const int wrap = (s > 8) ? (s - 8) : 0;   // IDX[s] = {0..wrap-1}++{s..15}

    #pragma unroll 1
    for (int ch = 0; ch < CHUNK; ++ch) {
        const int rbase = b0 + ch * 256;

        // ---- phase 1: gather z for own row, pack, write planes ----
        {
            const int row = rbase + tid;
            float zs[8];
            #pragma unroll
            for (int j = 0; j < 8; ++j) {
                const int idx = (j < wrap) ? j : (s + j - wrap);  // uniform
                zs[j] = (idx < 8) ? x_f[row * 8 + idx] : x_b[row * 8 + (idx - 8)];
            }
            const float4 uv = *(const float4*)(u + row * 4);
            zplA[tid] = make_uint4(h2_bits(pack2(zs[0], zs[1])), h2_bits(pack2(zs[2], zs[3])),
                                   h2_bits(pack2(zs[4], zs[5])), h2_bits(pack2(zs[6], zs[7])));
            zplB[tid] = make_uint2(h2_bits(pack2(uv.x, uv.y)), h2_bits(pack2(uv.z, uv.w)));
        }
        // No barrier: wave w reads only rows [64w,64w+64) it wrote itself;
        // weight LDS is read-only after the initial sync.

        // ---- phase 2: two 32-row tiles ----
        #pragma unroll
        for (int m = 0; m < 2; ++m) {
            const int rowb = 64 * w + 32 * m;

            // Opaque zero: defeats LICM/CSE so weight ds_reads stay per-tile
            // (normal HIP loads -> compiler manages lgkmcnt; just un-hoistable).
            unsigned int zero = 0;
            asm("" : "+v"(zero));
            const int lz = lid + (int)zero;

            // z B-frag: B[k=8h+j][n]: h=0 -> z dwords 0..3; h=1 -> u pair + 0
            f16x8 zf;
            if (h == 0) {
                zf = u4_to_h8(zplA[rowb + n]);
            } else {
                const uint2 b = zplB[rowb + n];
                zf = u4_to_h8(make_uint4(b.x, b.y, 0u, 0u));
            }

            const f32x16 z16 = {0.f,0.f,0.f,0.f,0.f,0.f,0.f,0.f,
                                0.f,0.f,0.f,0.f,0.f,0.f,0.f,0.f};
            f32x16 c2a = z16, c2b = z16;

            // ---- half A: c1 covers feats 0..31 -> tanh -> kc0, kc1 ----
            // (kc0/kc1's B-frags need only these feats; c1 then dead, its
            //  regs reused for half B. sched_barrier pins the lifetime.)
            #pragma unroll
            for (int half = 0; half < 2; ++half) {
                const f16x8 a0f = u4_to_h8(sA0[half][lz]);
                f32x16 c1 = __builtin_amdgcn_mfma_f32_32x32x16_f16(a0f, zf, z16, 0, 0, 0);
                unsigned int t[8];
                #pragma unroll
                for (int a = 0; a < 4; ++a) {
                    t[2 * a + 0] = h2_bits(tanh_pk(pack2(c1[4 * a],     c1[4 * a + 1])));
                    t[2 * a + 1] = h2_bits(tanh_pk(pack2(c1[4 * a + 2], c1[4 * a + 3])));
                }
                __builtin_amdgcn_sched_barrier(0);
                #pragma unroll
                for (int kk = 0; kk < 2; ++kk) {
                    const int kc = 2 * half + kk;         // 0..3
                    const int q  = 4 * kk;
                    u32x2 r0 = __builtin_amdgcn_permlane32_swap(t[q + 0], t[q + 2], false, false);
                    u32x2 r1 = __builtin_amdgcn_permlane32_swap(t[q + 1], t[q + 3], false, false);
                    const f16x8 hb  = u4_to_h8(make_uint4(r0.x, r1.x, r0.y, r1.y));
                    const f16x8 w1a = u4_to_h8(sA1[kc][lz]);
                    const f16x8 w1b = u4_to_h8(sA1[4 + kc][lz]);
                    c2a = __builtin_amdgcn_mfma_f32_32x32x16_f16(w1a, hb, c2a, 0, 0, 0);
                    c2b = __builtin_amdgcn_mfma_f32_32x32x16_f16(w1b, hb, c2b, 0, 0, 0);
                }
                __builtin_amdgcn_sched_barrier(0);
            }

            // layer 3: packed tanh + v_dot2; W2 pairs broadcast-read from LDS.
            // Split accumulators: 2-deep chains instead of 4-deep.
            const unsigned int* w2z = &w2l[zero];
            float p0 = 0.f, p1 = 0.f, q0 = 0.f, q1 = 0.f;
            #pragma unroll
            for (int a = 0; a < 4; ++a) {
                const int r = 4 * a;
                const uint2 wa = *(const uint2*)&w2z[4 * a + 2 * h];        // Mh=0
                const uint2 wb = *(const uint2*)&w2z[16 + 4 * a + 2 * h];   // Mh=1
                if (a & 1) {
                    p1 = __builtin_amdgcn_fdot2(tanh_pk(pack2(c2a[r], c2a[r + 1])), bits_h2(wa.x), p1, false);
                    p1 = __builtin_amdgcn_fdot2(tanh_pk(pack2(c2a[r + 2], c2a[r + 3])), bits_h2(wa.y), p1, false);
                    q1 = __builtin_amdgcn_fdot2(tanh_pk(pack2(c2b[r], c2b[r + 1])), bits_h2(wb.x), q1, false);
                    q1 = __builtin_amdgcn_fdot2(tanh_pk(pack2(c2b[r + 2], c2b[r + 3])), bits_h2(wb.y), q1, false);
                } else {
                    p0 = __builtin_amdgcn_fdot2(tanh_pk(pack2(c2a[r], c2a[r + 1])), bits_h2(wa.x), p0, false);
                    p0 = __builtin_amdgcn_fdot2(tanh_pk(pack2(c2a[r + 2], c2a[r + 3])), bits_h2(wa.y), p0, false);
                    q0 = __builtin_amdgcn_fdot2(tanh_pk(pack2(c2b[r], c2b[r + 1])), bits_h2(wb.x), q0, false);
                    q0 = __builtin_amdgcn_fdot2(tanh_pk(pack2(c2b[r + 2], c2b[r + 3])), bits_h2(wb.y), q0, false);
                }
            }
            float acc = (p0 + p1) + (q0 + q1);
            acc += __shfl_xor(acc, 32);       // combine h=0/h=1 halves

            if (lid < 32)
                out[(rbase + rowb + n) * N_STATES + s] = acc;
        }
    }
}

extern "C" void kernel_launch(void* const* d_in, const int* in_sizes, int n_in,
                              void* d_out, int out_size, void* d_ws, size_t ws_size,
                              hipStream_t stream) {
    const float* x_f = (const float*)d_in[0];
    const float* x_b = (const float*)d_in[1];
    const float* u   = (const float*)d_in[2];
    const float* W0  = (const float*)d_in[3];
    const float* W1  = (const float*)d_in[4];
    const float* W2  = (const float*)d_in[5];
    float* out = (float*)d_out;

    const int nb = in_sizes[0] / 8;                 // 131072 = 128 * 1024
    dim3 grid(nb / (256 * CHUNK), N_STATES);        // (128, 16) = 2048 blocks
    fans_mfma_kernel<<<grid, 256, 0, stream>>>(x_f, x_b, u, W0, W1, W2, out);
}

// Round 7
// 121.087 us; speedup vs baseline: 1.0780x; 1.0102x over previous
//
#include <hip/hip_runtime.h>

// FANS: B=131072 rows x 16 states, MLP 12->64->64->1 with tanh, fp32 in/out.
// R23: kill the accvgpr shuttle. Evidence chain: VALU busy-TIME constant
// ~42us across R17/R20/R22 regardless of structure; VGPR_Count=36 can't hold
// the 48 accum regs (c1+c2a+c2b) -> launch_bounds(256,6)'s 85-reg budget
// forced accums into AGPRs -> every tanh input = v_accvgpr_read, every tile
// re-zero = v_accvgpr_write: ~96 extra VALU ops/tile (~25-30% of all VALU),
// exactly the gap between op-count model (~18us) and measured busy (~42us).
// Change (single, for attribution): launch_bounds (256,6) -> (256,4).
// Budget 128 regs -> accums live in arch VGPRs (gfx950 MFMA D/C in v[] is
// native), shuttle vanishes. Occupancy ceiling 4 waves/SIMD = the 50% we
// already measure, so this isolates the VALU-op cut.
// Confirmation signal: VGPR_Count jumps to ~95-115. Tripwires: FETCH>>10MB
// -> spill, revert; VGPR stays <=48 -> compiler kept AGPRs, drop bounds
// entirely next; VGPR high but dur flat -> shuttle theory wrong, pivot to
// intrinsic VALU cuts (degree-3 tanh, phase-1 dedup).
// Kept from R22: sequential c1-half lifetimes + sched_barrier pins,
// permlane32_swap H-exchange, 32x32x16 MFMA, pk-f16 tanh, weights in LDS
// frag layout, opaque-zero anti-LICM, CHUNK=4, split fdot2 accums.

#define N_STATES 16
#define CHUNK    4

typedef _Float16 f16x8  __attribute__((ext_vector_type(8)));
typedef float    f32x16 __attribute__((ext_vector_type(16)));
typedef __fp16   h2     __attribute__((ext_vector_type(2)));
typedef unsigned int u32x2 __attribute__((ext_vector_type(2)));

__device__ __forceinline__ h2 pack2(float a, float b) {
    return __builtin_amdgcn_cvt_pkrtz(a, b);
}
__device__ __forceinline__ unsigned int h2_bits(h2 v) {
    union { h2 h; unsigned int u; } x; x.h = v; return x.u;
}
__device__ __forceinline__ h2 bits_h2(unsigned int v) {
    union { unsigned int u; h2 h; } x; x.u = v; return x.h;
}
__device__ __forceinline__ f16x8 u4_to_h8(uint4 v) {
    union { uint4 u; f16x8 h; } x; x.u = v; return x.h;
}
__device__ __forceinline__ uint4 pk8(float4 a, float4 b) {
    return make_uint4(h2_bits(pack2(a.x, a.y)), h2_bits(pack2(a.z, a.w)),
                      h2_bits(pack2(b.x, b.y)), h2_bits(pack2(b.z, b.w)));
}

// Packed-f16 tanh: clamp(+-1.25) then odd Chebyshev poly; v_pk_* full-rate.
__device__ __forceinline__ h2 tanh_pk(h2 x) {
    const h2 hi = {(__fp16)1.25f, (__fp16)1.25f};
    const h2 lo = {(__fp16)-1.25f, (__fp16)-1.25f};
    x = __builtin_elementwise_min(__builtin_elementwise_max(x, lo), hi);
    h2 s = x * x;
    const h2 c4 = {(__fp16)0.00598591f, (__fp16)0.00598591f};
    const h2 c3 = {(__fp16)-0.03807894f, (__fp16)-0.03807894f};
    const h2 c2 = {(__fp16)0.12576901f, (__fp16)0.12576901f};
    const h2 c1 = {(__fp16)-0.33203310f, (__fp16)-0.33203310f};
    const h2 c0 = {(__fp16)0.99998110f, (__fp16)0.99998110f};
    h2 p = s * c4 + c3;
    p = s * p + c2;
    p = s * p + c1;
    p = s * p + c0;
    return x * p;
}

__global__ __launch_bounds__(256, 4) void fans_mfma_kernel(
    const float* __restrict__ x_f, const float* __restrict__ x_b,
    const float* __restrict__ u,   const float* __restrict__ W0,
    const float* __restrict__ W1,  const float* __restrict__ W2,
    float* __restrict__ out)
{
    __shared__ __align__(16) uint4 zplA[256];              // 4 KB: z dwords 0..3
    __shared__ __align__(16) uint2 zplB[256];              // 2 KB: u pair
    __shared__ __align__(16) uint4 sA1[8][64];             // 8 KB: W1 frags [Mh*4+kc][h*32+n]
    __shared__ __align__(16) uint4 sA0[2][64];             // 2 KB: W0 frags [Mh][h*32+n]
    __shared__ __align__(16) unsigned int w2l[32];         // 128 B: W2 pair-packed

    const int s   = blockIdx.y;
    const int tid = threadIdx.x;
    const int b0  = blockIdx.x * (256 * CHUNK);

    const int lid = tid & 63;
    const int w   = tid >> 6;     // wave id; wave w owns local rows [64w,64w+64)
    const int n   = lid & 31;     // batch row within 32-tile / feat row for A
    const int h   = lid >> 5;     // K-half (k = 8h+j)

    // ---- stage weights to LDS in frag layout (once per block) ----
    // sA1[Mh*4+kc][h*32+n] = W1[s][32Mh+n][16kc+8h+0..7] as 8 x f16
    {
        const int r  = tid >> 2;          // 0..63 feature row
        const int kc = tid & 3;           // 0..3 K-chunk
        const float* p = W1 + s * 4096 + r * 64 + kc * 16;
        const float4 v0 = ((const float4*)p)[0];
        const float4 v1 = ((const float4*)p)[1];
        const float4 v2 = ((const float4*)p)[2];
        const float4 v3 = ((const float4*)p)[3];
        sA1[(r >> 5) * 4 + kc][(r & 31)]      = pk8(v0, v1);  // h=0: cols +0..7
        sA1[(r >> 5) * 4 + kc][32 + (r & 31)] = pk8(v2, v3);  // h=1: cols +8..15
    }
    // sA0[Mh][h*32+n] = W0[s][32Mh+n][8h+0..7] (h=1: cols 8..11 + zero pad)
    if (tid < 128) {
        const int r  = tid >> 1;          // 0..63 feature row
        const int hh = tid & 1;
        const float* base = W0 + s * 768 + r * 12;
        uint4 v;
        if (hh == 0) {
            const float4 v0 = *(const float4*)(base + 0);
            const float4 v1 = *(const float4*)(base + 4);
            v = pk8(v0, v1);
        } else {
            const float4 v0 = *(const float4*)(base + 8);   // k=8..11
            v = make_uint4(h2_bits(pack2(v0.x, v0.y)), h2_bits(pack2(v0.z, v0.w)), 0u, 0u);
        }
        sA0[r >> 5][hh * 32 + (r & 31)] = v;
    }
    // w2l[i] = pack2(W2[s][2i], W2[s][2i+1]); layer-3 reads broadcast per h.
    if (tid < 32) {
        const float* w2s = W2 + s * 64;
        w2l[tid] = h2_bits(pack2(w2s[2 * tid], w2s[2 * tid + 1]));
    }
    __syncthreads();

    const int wrap = (s > 8) ? (s - 8) : 0;   // IDX[s] = {0..wrap-1}++{s..15}

    #pragma unroll 1
    for (int ch = 0; ch < CHUNK; ++ch) {
        const int rbase = b0 + ch * 256;

        // ---- phase 1: gather z for own row, pack, write planes ----
        {
            const int row = rbase + tid;
            float zs[8];
            #pragma unroll
            for (int j = 0; j < 8; ++j) {
                const int idx = (j < wrap) ? j : (s + j - wrap);  // uniform
                zs[j] = (idx < 8) ? x_f[row * 8 + idx] : x_b[row * 8 + (idx - 8)];
            }
            const float4 uv = *(const float4*)(u + row * 4);
            zplA[tid] = make_uint4(h2_bits(pack2(zs[0], zs[1])), h2_bits(pack2(zs[2], zs[3])),
                                   h2_bits(pack2(zs[4], zs[5])), h2_bits(pack2(zs[6], zs[7])));
            zplB[tid] = make_uint2(h2_bits(pack2(uv.x, uv.y)), h2_bits(pack2(uv.z, uv.w)));
        }
        // No barrier: wave w reads only rows [64w,64w+64) it wrote itself;
        // weight LDS is read-only after the initial sync.

        // ---- phase 2: two 32-row tiles ----
        #pragma unroll
        for (int m = 0; m < 2; ++m) {
            const int rowb = 64 * w + 32 * m;

            // Opaque zero: defeats LICM/CSE so weight ds_reads stay per-tile
            // (normal HIP loads -> compiler manages lgkmcnt; just un-hoistable).
            unsigned int zero = 0;
            asm("" : "+v"(zero));
            const int lz = lid + (int)zero;

            // z B-frag: B[k=8h+j][n]: h=0 -> z dwords 0..3; h=1 -> u pair + 0
            f16x8 zf;
            if (h == 0) {
                zf = u4_to_h8(zplA[rowb + n]);
            } else {
                const uint2 b = zplB[rowb + n];
                zf = u4_to_h8(make_uint4(b.x, b.y, 0u, 0u));
            }

            const f32x16 z16 = {0.f,0.f,0.f,0.f,0.f,0.f,0.f,0.f,
                                0.f,0.f,0.f,0.f,0.f,0.f,0.f,0.f};
            f32x16 c2a = z16, c2b = z16;

            // ---- half A: c1 covers feats 0..31 -> tanh -> kc0, kc1 ----
            // (kc0/kc1's B-frags need only these feats; c1 then dead, its
            //  regs reused for half B. sched_barrier pins the lifetime.)
            #pragma unroll
            for (int half = 0; half < 2; ++half) {
                const f16x8 a0f = u4_to_h8(sA0[half][lz]);
                f32x16 c1 = __builtin_amdgcn_mfma_f32_32x32x16_f16(a0f, zf, z16, 0, 0, 0);
                unsigned int t[8];
                #pragma unroll
                for (int a = 0; a < 4; ++a) {
                    t[2 * a + 0] = h2_bits(tanh_pk(pack2(c1[4 * a],     c1[4 * a + 1])));
                    t[2 * a + 1] = h2_bits(tanh_pk(pack2(c1[4 * a + 2], c1[4 * a + 3])));
                }
                __builtin_amdgcn_sched_barrier(0);
                #pragma unroll
                for (int kk = 0; kk < 2; ++kk) {
                    const int kc = 2 * half + kk;         // 0..3
                    const int q  = 4 * kk;
                    u32x2 r0 = __builtin_amdgcn_permlane32_swap(t[q + 0], t[q + 2], false, false);
                    u32x2 r1 = __builtin_amdgcn_permlane32_swap(t[q + 1], t[q + 3], false, false);
                    const f16x8 hb  = u4_to_h8(make_uint4(r0.x, r1.x, r0.y, r1.y));
                    const f16x8 w1a = u4_to_h8(sA1[kc][lz]);
                    const f16x8 w1b = u4_to_h8(sA1[4 + kc][lz]);
                    c2a = __builtin_amdgcn_mfma_f32_32x32x16_f16(w1a, hb, c2a, 0, 0, 0);
                    c2b = __builtin_amdgcn_mfma_f32_32x32x16_f16(w1b, hb, c2b, 0, 0, 0);
                }
                __builtin_amdgcn_sched_barrier(0);
            }

            // layer 3: packed tanh + v_dot2; W2 pairs broadcast-read from LDS.
            // Split accumulators: 2-deep chains instead of 4-deep.
            const unsigned int* w2z = &w2l[zero];
            float p0 = 0.f, p1 = 0.f, q0 = 0.f, q1 = 0.f;
            #pragma unroll
            for (int a = 0; a < 4; ++a) {
                const int r = 4 * a;
                const uint2 wa = *(const uint2*)&w2z[4 * a + 2 * h];        // Mh=0
                const uint2 wb = *(const uint2*)&w2z[16 + 4 * a + 2 * h];   // Mh=1
                if (a & 1) {
                    p1 = __builtin_amdgcn_fdot2(tanh_pk(pack2(c2a[r], c2a[r + 1])), bits_h2(wa.x), p1, false);
                    p1 = __builtin_amdgcn_fdot2(tanh_pk(pack2(c2a[r + 2], c2a[r + 3])), bits_h2(wa.y), p1, false);
                    q1 = __builtin_amdgcn_fdot2(tanh_pk(pack2(c2b[r], c2b[r + 1])), bits_h2(wb.x), q1, false);
                    q1 = __builtin_amdgcn_fdot2(tanh_pk(pack2(c2b[r + 2], c2b[r + 3])), bits_h2(wb.y), q1, false);
                } else {
                    p0 = __builtin_amdgcn_fdot2(tanh_pk(pack2(c2a[r], c2a[r + 1])), bits_h2(wa.x), p0, false);
                    p0 = __builtin_amdgcn_fdot2(tanh_pk(pack2(c2a[r + 2], c2a[r + 3])), bits_h2(wa.y), p0, false);
                    q0 = __builtin_amdgcn_fdot2(tanh_pk(pack2(c2b[r], c2b[r + 1])), bits_h2(wb.x), q0, false);
                    q0 = __builtin_amdgcn_fdot2(tanh_pk(pack2(c2b[r + 2], c2b[r + 3])), bits_h2(wb.y), q0, false);
                }
            }
            float acc = (p0 + p1) + (q0 + q1);
            acc += __shfl_xor(acc, 32);       // combine h=0/h=1 halves

            if (lid < 32)
                out[(rbase + rowb + n) * N_STATES + s] = acc;
        }
    }
}

extern "C" void kernel_launch(void* const* d_in, const int* in_sizes, int n_in,
                              void* d_out, int out_size, void* d_ws, size_t ws_size,
                              hipStream_t stream) {
    const float* x_f = (const float*)d_in[0];
    const float* x_b = (const float*)d_in[1];
    const float* u   = (const float*)d_in[2];
    const float* W0  = (const float*)d_in[3];
    const float* W1  = (const float*)d_in[4];
    const float* W2  = (const float*)d_in[5];
    float* out = (float*)d_out;

    const int nb = in_sizes[0] / 8;                 // 131072 = 128 * 1024
    dim3 grid(nb / (256 * CHUNK), N_STATES);        // (128, 16) = 2048 blocks
    fans_mfma_kernel<<<grid, 256, 0, stream>>>(x_f, x_b, u, W0, W1, W2, out);
}